// Round 1
// baseline (366.641 us; speedup 1.0000x reference)
//
#include <hip/hip_runtime.h>
#include <math.h>

// Problem constants (B=32, T=512, F=64, H=64, E=32)
#define NTOK   16384   // B*T
#define FD     64
#define HD     64
#define ED     32

__device__ __forceinline__ float eluf(float z) {
    return z > 0.0f ? z : (expf(z) - 1.0f);
}

// One block = 64 tokens, 256 threads (4 waves).
// Phase 1: gating network -> w_t tile in LDS (softmax over F).
// Phase 2: per-feature experts as f-chunked GEMM with on-the-fly A:
//   out[t,k] = sum_f sum_h (w_t[t,f]*elu(x[t,f]*ew1[f,h]+eb1[f,h])) * ew3[f,h,k]
//            + sum_f w_t[t,f]*eb3[f,k]          (folded in as K-row 64)
__global__ __launch_bounds__(256)
void moe_fused(const float* __restrict__ x,   const float* __restrict__ s,
               const float* __restrict__ fw1, const float* __restrict__ fb1,
               const float* __restrict__ fw2, const float* __restrict__ fb2,
               const float* __restrict__ fw3, const float* __restrict__ fb3,
               const float* __restrict__ ew1, const float* __restrict__ eb1,
               const float* __restrict__ ew3, const float* __restrict__ eb3,
               float* __restrict__ out)
{
    // stride-65 rows => bank = (row + col) % 32 patterns, conflict-free
    __shared__ __align__(16) float wts[64 * 65];   // [t][f], gate weights
    __shared__ __align__(16) float W3s[65 * 64];   // rows 0..63: W3_f[h][k]; row 64: eb3[f][k]
    __shared__ __align__(16) float hs [65 * 65];   // [h][t]; row 64: w_t[t][f]
    __shared__ float egs[4][64];                   // per-wave elu(g)

    const int tid     = threadIdx.x;
    const int wave    = tid >> 6;
    const int lane    = tid & 63;
    const int tokbase = blockIdx.x * 64;

    // ---------------- Phase 1: gating -> wts ----------------
    for (int i = 0; i < 16; ++i) {
        const int t = i * 4 + wave;                 // token within tile
        const float* xrow = x + (size_t)(tokbase + t) * FD;
        const float* srow = s + (size_t)(tokbase + t) * ED;

        float g = fb1[lane] + fb2[lane];
        #pragma unroll 16
        for (int f = 0; f < FD; ++f) g = fmaf(xrow[f], fw1[f * HD + lane], g);
        #pragma unroll 16
        for (int e = 0; e < ED; ++e) g = fmaf(srow[e], fw2[e * HD + lane], g);
        egs[wave][lane] = eluf(g);
        __syncthreads();

        float lg = fb3[lane];
        #pragma unroll 16
        for (int h = 0; h < HD; ++h) lg = fmaf(egs[wave][h], fw3[h * FD + lane], lg);

        // softmax across the 64 lanes (feature axis)
        float m = lg;
        #pragma unroll
        for (int off = 32; off > 0; off >>= 1) m = fmaxf(m, __shfl_xor(m, off));
        float p = expf(lg - m);
        float sm = p;
        #pragma unroll
        for (int off = 32; off > 0; off >>= 1) sm += __shfl_xor(sm, off);
        wts[t * 65 + lane] = p / sm;
        __syncthreads();
    }

    // ---------------- Phase 2: experts ----------------
    float acc[4][4];
    #pragma unroll
    for (int i = 0; i < 4; ++i)
        #pragma unroll
        for (int j = 0; j < 4; ++j) acc[i][j] = 0.0f;

    const int tg = tid >> 4;      // 0..15 -> tokens tg*4..tg*4+3
    const int kg = tid & 15;      // 0..15 -> k kg*4..kg*4+3
    const int t0 = tg * 4, k0 = kg * 4;
    const int hrow  = tid & 63;   // h this thread stages
    const int tquad = tid >> 6;   // 0..3

    for (int f = 0; f < FD; ++f) {
        // stage W3_f[h][k] (coalesced float4) + eb3 row
        const float* w3f = ew3 + (size_t)f * (HD * HD);
        #pragma unroll
        for (int r = 0; r < 4; ++r) {
            const int idx = r * 1024 + tid * 4;
            *(float4*)&W3s[idx] = *(const float4*)&w3f[idx];
        }
        if (tid < 64) W3s[64 * 64 + tid] = eb3[f * HD + tid];

        // stage h~[h][t] = w_t[t][f] * elu(x[t][f]*ew1[f][h] + eb1[f][h])
        const float w1h = ew1[f * HD + hrow];
        const float b1h = eb1[f * HD + hrow];
        #pragma unroll
        for (int j = 0; j < 16; ++j) {
            const int t = tquad * 16 + j;
            const float xv = x[(size_t)(tokbase + t) * FD + f];   // wave-uniform, L1-hot
            hs[hrow * 65 + t] = wts[t * 65 + f] * eluf(fmaf(xv, w1h, b1h));
        }
        if (tid < 64) hs[64 * 65 + tid] = wts[tid * 65 + f];   // bias "K-row"
        __syncthreads();

        // 4x4 register tile over K=65
        for (int h = 0; h < 65; ++h) {
            const float4 wv = *(const float4*)&W3s[h * 64 + k0];
            const float a0 = hs[h * 65 + t0 + 0];
            const float a1 = hs[h * 65 + t0 + 1];
            const float a2 = hs[h * 65 + t0 + 2];
            const float a3 = hs[h * 65 + t0 + 3];
            acc[0][0] = fmaf(a0, wv.x, acc[0][0]);
            acc[0][1] = fmaf(a0, wv.y, acc[0][1]);
            acc[0][2] = fmaf(a0, wv.z, acc[0][2]);
            acc[0][3] = fmaf(a0, wv.w, acc[0][3]);
            acc[1][0] = fmaf(a1, wv.x, acc[1][0]);
            acc[1][1] = fmaf(a1, wv.y, acc[1][1]);
            acc[1][2] = fmaf(a1, wv.z, acc[1][2]);
            acc[1][3] = fmaf(a1, wv.w, acc[1][3]);
            acc[2][0] = fmaf(a2, wv.x, acc[2][0]);
            acc[2][1] = fmaf(a2, wv.y, acc[2][1]);
            acc[2][2] = fmaf(a2, wv.z, acc[2][2]);
            acc[2][3] = fmaf(a2, wv.w, acc[2][3]);
            acc[3][0] = fmaf(a3, wv.x, acc[3][0]);
            acc[3][1] = fmaf(a3, wv.y, acc[3][1]);
            acc[3][2] = fmaf(a3, wv.z, acc[3][2]);
            acc[3][3] = fmaf(a3, wv.w, acc[3][3]);
        }
        __syncthreads();
    }

    // ---------------- epilogue ----------------
    #pragma unroll
    for (int i = 0; i < 4; ++i) {
        float4 o;
        o.x = acc[i][0]; o.y = acc[i][1]; o.z = acc[i][2]; o.w = acc[i][3];
        *(float4*)&out[(size_t)(tokbase + t0 + i) * HD + k0] = o;
    }
}

extern "C" void kernel_launch(void* const* d_in, const int* in_sizes, int n_in,
                              void* d_out, int out_size, void* d_ws, size_t ws_size,
                              hipStream_t stream) {
    const float* x   = (const float*)d_in[0];
    const float* s   = (const float*)d_in[1];
    const float* fw1 = (const float*)d_in[2];
    const float* fb1 = (const float*)d_in[3];
    const float* fw2 = (const float*)d_in[4];
    const float* fb2 = (const float*)d_in[5];
    const float* fb2_unused __attribute__((unused)) = fb2;
    const float* fw3 = (const float*)d_in[6];
    const float* fb3 = (const float*)d_in[7];
    const float* ew1 = (const float*)d_in[8];
    const float* eb1 = (const float*)d_in[9];
    const float* ew3 = (const float*)d_in[10];
    const float* eb3 = (const float*)d_in[11];
    float* out = (float*)d_out;

    dim3 grid(NTOK / 64);   // 256 blocks, 64 tokens each
    dim3 block(256);
    moe_fused<<<grid, block, 0, stream>>>(x, s, fw1, fb1, fw2, fb2, fw3, fb3,
                                          ew1, eb1, ew3, eb3, out);
}

// Round 2
// 184.694 us; speedup vs baseline: 1.9851x; 1.9851x over previous
//
#include <hip/hip_runtime.h>
#include <math.h>

// B=32,T=512 -> NTOK=16384 tokens; F=64 features; H=64 hidden; E=32
#define NTOK 16384
#define TPB  64                 // tokens per block
#define NBLK (NTOK / TPB)       // 256 blocks

typedef __attribute__((ext_vector_type(8))) short short8;   // 8 bf16
typedef __attribute__((ext_vector_type(4))) float f32x4;    // MFMA acc

__device__ __forceinline__ unsigned short bf16_rne(float x) {
    unsigned int u = __float_as_uint(x);
    u += 0x7fffu + ((u >> 16) & 1u);
    return (unsigned short)(u >> 16);
}
__device__ __forceinline__ float eluf(float z) {
    return z > 0.0f ? z : (__expf(z) - 1.0f);
}

// ---------------- pre-pass: build bf16, XOR-swizzled LDS images in ws ----------------
// blocks 0..63: ew3[f] (64x64 [h][k]) -> image of W3^T: elem(k,h) at k*64 + ((h>>3)^(k&7))*8 + (h&7)
// block 64:     eb3    (64x64 [f][k]) -> image of eb3^T: elem(k,f) same formula (row=f, col=k)
__global__ __launch_bounds__(256)
void prepass(const float* __restrict__ ew3, const float* __restrict__ eb3,
             unsigned short* __restrict__ ws) {
    __shared__ float tile[64 * 65];
    const int bid = blockIdx.x, tid = threadIdx.x;
    const float* src = (bid < 64) ? (ew3 + (size_t)bid * 4096) : eb3;

    const int r = tid >> 2, c0 = (tid & 3) * 16;     // coalesced load [r][c]
    #pragma unroll
    for (int j = 0; j < 4; ++j) {
        float4 v = *(const float4*)(src + r * 64 + c0 + j * 4);
        tile[r * 65 + c0 + j * 4 + 0] = v.x;
        tile[r * 65 + c0 + j * 4 + 1] = v.y;
        tile[r * 65 + c0 + j * 4 + 2] = v.z;
        tile[r * 65 + c0 + j * 4 + 3] = v.w;
    }
    __syncthreads();

    unsigned short* dst = ws + (size_t)bid * 4096;
    const int k = tid >> 2, h0 = (tid & 3) * 16;     // write transposed image
    #pragma unroll
    for (int jb = 0; jb < 2; ++jb) {
        unsigned int pw[4];
        #pragma unroll
        for (int p = 0; p < 4; ++p) {
            unsigned int lo = bf16_rne(tile[(h0 + jb * 8 + 2 * p    ) * 65 + k]);
            unsigned int hi = bf16_rne(tile[(h0 + jb * 8 + 2 * p + 1) * 65 + k]);
            pw[p] = lo | (hi << 16);
        }
        const int cb = ((h0 >> 3) + jb) ^ (k & 7);
        uint4 pk; pk.x = pw[0]; pk.y = pw[1]; pk.z = pw[2]; pk.w = pw[3];
        *(uint4*)(dst + k * 64 + cb * 8) = pk;
    }
}

// ---------------- main fused kernel ----------------
__global__ __launch_bounds__(256)
void moe_fused(const float* __restrict__ x,   const float* __restrict__ s,
               const float* __restrict__ fw1, const float* __restrict__ fb1,
               const float* __restrict__ fw2, const float* __restrict__ fb2,
               const float* __restrict__ fw3, const float* __restrict__ fb3,
               const float* __restrict__ ew1, const float* __restrict__ eb1,
               const float* __restrict__ ew3, const float* __restrict__ eb3,
               const unsigned short* __restrict__ w3img, int use_ws,
               float* __restrict__ out)
{
    __shared__ float          wts[64 * 65];   // gate weights fp32 [t][f], stride 65 (bank-spread)
    __shared__ unsigned short wbf[64 * 64];   // gate weights bf16, A-operand XOR image [t][f]
    __shared__ unsigned short hls[64 * 64];   // h~ bf16, A-operand XOR image [t][h]
    __shared__ unsigned short w3ls[64 * 64];  // W3^T bf16, B-operand XOR image [n][h]
    __shared__ float          fscr[64 * 65];  // fallback transpose scratch

    const int tid = threadIdx.x;
    const int wv = tid >> 6, lane = tid & 63;
    const int tokbase = blockIdx.x * TPB;

    // ================= Phase 1: gating (f-outer, weights in VGPR, readlane bcast) ============
    {
        const int t0w = wv * 16;
        const float* xw = x + (size_t)(tokbase + t0w) * 64;
        const float* sw = s + (size_t)(tokbase + t0w) * 32;

        float g[16];
        const float b0 = fb1[lane] + fb2[lane];
        #pragma unroll
        for (int t = 0; t < 16; ++t) g[t] = b0;

        for (int f = 0; f < 64; ++f) {
            const float w = fw1[f * 64 + lane];
            #pragma unroll
            for (int t = 0; t < 16; ++t) g[t] = fmaf(xw[t * 64 + f], w, g[t]);
        }
        for (int e = 0; e < 32; ++e) {
            const float w = fw2[e * 64 + lane];
            #pragma unroll
            for (int t = 0; t < 16; ++t) g[t] = fmaf(sw[t * 32 + e], w, g[t]);
        }
        #pragma unroll
        for (int t = 0; t < 16; ++t) g[t] = eluf(g[t]);

        float lg[16];
        const float b3 = fb3[lane];
        #pragma unroll
        for (int t = 0; t < 16; ++t) lg[t] = b3;
        for (int h = 0; h < 64; ++h) {
            const float w = fw3[h * 64 + lane];
            #pragma unroll
            for (int t = 0; t < 16; ++t) {
                const float ev = __int_as_float(
                    __builtin_amdgcn_readlane(__float_as_int(g[t]), h));
                lg[t] = fmaf(ev, w, lg[t]);
            }
        }
        // softmax across 64 lanes (feature axis), write wts fp32 + wbf bf16 image
        #pragma unroll
        for (int t = 0; t < 16; ++t) {
            float m = lg[t];
            #pragma unroll
            for (int off = 32; off > 0; off >>= 1) m = fmaxf(m, __shfl_xor(m, off));
            const float p = __expf(lg[t] - m);
            float sm = p;
            #pragma unroll
            for (int off = 32; off > 0; off >>= 1) sm += __shfl_xor(sm, off);
            const float w = p / sm;
            const int tt = t0w + t;
            wts[tt * 65 + lane] = w;
            wbf[tt * 64 + (((lane >> 3) ^ (tt & 7)) * 8) + (lane & 7)] = bf16_rne(w);
        }
    }
    __syncthreads();

    // ================= Phase 2: experts via MFMA ============
    const int tM = (wv & 1) * 32;          // wave's 32-token strip
    const int tN = (wv >> 1) * 32;         // wave's 32-output strip
    const int lm = tid & 15, quad = (tid >> 4) & 3;
    const int hb = tid & 7, h0 = hb * 8, tq = tid >> 3;   // h~ staging assignment

    f32x4 acc[2][2];
    #pragma unroll
    for (int i = 0; i < 2; ++i)
        #pragma unroll
        for (int j = 0; j < 2; ++j) acc[i][j] = (f32x4){0.f, 0.f, 0.f, 0.f};

    for (int f = 0; f < 64; ++f) {
        // ---- stage W3^T bf16 image into w3ls ----
        if (use_ws) {
            const uint4* src = (const uint4*)(w3img + (size_t)f * 4096);
            uint4 v0 = src[tid], v1 = src[tid + 256];
            ((uint4*)w3ls)[tid] = v0;
            ((uint4*)w3ls)[tid + 256] = v1;
        } else {
            const float* w3f = ew3 + (size_t)f * 4096;
            const int r = tid >> 2, c0 = (tid & 3) * 16;
            #pragma unroll
            for (int j = 0; j < 4; ++j) {
                float4 v = *(const float4*)(w3f + r * 64 + c0 + j * 4);
                fscr[r * 65 + c0 + j * 4 + 0] = v.x;
                fscr[r * 65 + c0 + j * 4 + 1] = v.y;
                fscr[r * 65 + c0 + j * 4 + 2] = v.z;
                fscr[r * 65 + c0 + j * 4 + 3] = v.w;
            }
            __syncthreads();
            const int k = tid >> 2, hh0 = (tid & 3) * 16;
            #pragma unroll
            for (int jb = 0; jb < 2; ++jb) {
                unsigned int pw[4];
                #pragma unroll
                for (int p = 0; p < 4; ++p) {
                    unsigned int lo = bf16_rne(fscr[(hh0 + jb * 8 + 2 * p    ) * 65 + k]);
                    unsigned int hi = bf16_rne(fscr[(hh0 + jb * 8 + 2 * p + 1) * 65 + k]);
                    pw[p] = lo | (hi << 16);
                }
                const int cb = ((hh0 >> 3) + jb) ^ (k & 7);
                uint4 pk; pk.x = pw[0]; pk.y = pw[1]; pk.z = pw[2]; pk.w = pw[3];
                *(uint4*)(w3ls + k * 64 + cb * 8) = pk;
            }
        }

        // ---- generate h~ = w_t * elu(x*w1+b1) into hls (bf16 XOR image) ----
        const float4 w1a = *(const float4*)(ew1 + f * 64 + h0);
        const float4 w1b = *(const float4*)(ew1 + f * 64 + h0 + 4);
        const float4 b1a = *(const float4*)(eb1 + f * 64 + h0);
        const float4 b1b = *(const float4*)(eb1 + f * 64 + h0 + 4);
        const float w1r[8] = {w1a.x, w1a.y, w1a.z, w1a.w, w1b.x, w1b.y, w1b.z, w1b.w};
        const float b1r[8] = {b1a.x, b1a.y, b1a.z, b1a.w, b1b.x, b1b.y, b1b.z, b1b.w};
        #pragma unroll
        for (int half = 0; half < 2; ++half) {
            const int tt = tq + half * 32;
            const float wt = wts[tt * 65 + f];
            const float xv = x[(size_t)(tokbase + tt) * 64 + f];
            unsigned int pw[4];
            #pragma unroll
            for (int p = 0; p < 4; ++p) {
                const float v0 = wt * eluf(fmaf(xv, w1r[2 * p],     b1r[2 * p]));
                const float v1 = wt * eluf(fmaf(xv, w1r[2 * p + 1], b1r[2 * p + 1]));
                pw[p] = (unsigned int)bf16_rne(v0) | ((unsigned int)bf16_rne(v1) << 16);
            }
            uint4 pk; pk.x = pw[0]; pk.y = pw[1]; pk.z = pw[2]; pk.w = pw[3];
            *(uint4*)(hls + tt * 64 + ((hb ^ (tt & 7)) * 8)) = pk;
        }
        __syncthreads();

        // ---- MFMA: 2 M-tiles x 2 N-tiles x 2 K-chunks ----
        short8 a[2][2], b[2][2];
        #pragma unroll
        for (int sI = 0; sI < 2; ++sI)
            #pragma unroll
            for (int c = 0; c < 2; ++c) {
                const int t = tM + sI * 16 + lm;
                const int cb = (c * 4 + quad) ^ (t & 7);
                a[sI][c] = *(const short8*)(hls + t * 64 + cb * 8);
            }
        #pragma unroll
        for (int u = 0; u < 2; ++u)
            #pragma unroll
            for (int c = 0; c < 2; ++c) {
                const int n = tN + u * 16 + lm;
                const int cb = (c * 4 + quad) ^ (n & 7);
                b[u][c] = *(const short8*)(w3ls + n * 64 + cb * 8);
            }
        #pragma unroll
        for (int sI = 0; sI < 2; ++sI)
            #pragma unroll
            for (int u = 0; u < 2; ++u) {
                acc[sI][u] = __builtin_amdgcn_mfma_f32_16x16x32_bf16(a[sI][0], b[u][0], acc[sI][u], 0, 0, 0);
                acc[sI][u] = __builtin_amdgcn_mfma_f32_16x16x32_bf16(a[sI][1], b[u][1], acc[sI][u], 0, 0, 0);
            }
        __syncthreads();
    }

    // ---- bias pass: out += w_t @ eb3  (A = wbf image, B = eb3^T image) ----
    if (use_ws) {
        const uint4* src = (const uint4*)(w3img + (size_t)64 * 4096);
        uint4 v0 = src[tid], v1 = src[tid + 256];
        ((uint4*)w3ls)[tid] = v0;
        ((uint4*)w3ls)[tid + 256] = v1;
    } else {
        const int r = tid >> 2, c0 = (tid & 3) * 16;
        #pragma unroll
        for (int j = 0; j < 4; ++j) {
            float4 v = *(const float4*)(eb3 + r * 64 + c0 + j * 4);
            fscr[r * 65 + c0 + j * 4 + 0] = v.x;
            fscr[r * 65 + c0 + j * 4 + 1] = v.y;
            fscr[r * 65 + c0 + j * 4 + 2] = v.z;
            fscr[r * 65 + c0 + j * 4 + 3] = v.w;
        }
        __syncthreads();
        const int k = tid >> 2, hh0 = (tid & 3) * 16;
        #pragma unroll
        for (int jb = 0; jb < 2; ++jb) {
            unsigned int pw[4];
            #pragma unroll
            for (int p = 0; p < 4; ++p) {
                unsigned int lo = bf16_rne(fscr[(hh0 + jb * 8 + 2 * p    ) * 65 + k]);
                unsigned int hi = bf16_rne(fscr[(hh0 + jb * 8 + 2 * p + 1) * 65 + k]);
                pw[p] = lo | (hi << 16);
            }
            const int cb = ((hh0 >> 3) + jb) ^ (k & 7);
            uint4 pk; pk.x = pw[0]; pk.y = pw[1]; pk.z = pw[2]; pk.w = pw[3];
            *(uint4*)(w3ls + k * 64 + cb * 8) = pk;
        }
    }
    __syncthreads();
    {
        short8 a[2][2], b[2][2];
        #pragma unroll
        for (int sI = 0; sI < 2; ++sI)
            #pragma unroll
            for (int c = 0; c < 2; ++c) {
                const int t = tM + sI * 16 + lm;
                const int cb = (c * 4 + quad) ^ (t & 7);
                a[sI][c] = *(const short8*)(wbf + t * 64 + cb * 8);
            }
        #pragma unroll
        for (int u = 0; u < 2; ++u)
            #pragma unroll
            for (int c = 0; c < 2; ++c) {
                const int n = tN + u * 16 + lm;
                const int cb = (c * 4 + quad) ^ (n & 7);
                b[u][c] = *(const short8*)(w3ls + n * 64 + cb * 8);
            }
        #pragma unroll
        for (int sI = 0; sI < 2; ++sI)
            #pragma unroll
            for (int u = 0; u < 2; ++u) {
                acc[sI][u] = __builtin_amdgcn_mfma_f32_16x16x32_bf16(a[sI][0], b[u][0], acc[sI][u], 0, 0, 0);
                acc[sI][u] = __builtin_amdgcn_mfma_f32_16x16x32_bf16(a[sI][1], b[u][1], acc[sI][u], 0, 0, 0);
            }
    }

    // ---- epilogue: C-layout (col = lane&15, row = quad*4+reg) -> global fp32 ----
    #pragma unroll
    for (int sI = 0; sI < 2; ++sI)
        #pragma unroll
        for (int u = 0; u < 2; ++u)
            #pragma unroll
            for (int r = 0; r < 4; ++r) {
                const int tok = tokbase + tM + sI * 16 + quad * 4 + r;
                out[(size_t)tok * 64 + tN + u * 16 + lm] = acc[sI][u][r];
            }
}

extern "C" void kernel_launch(void* const* d_in, const int* in_sizes, int n_in,
                              void* d_out, int out_size, void* d_ws, size_t ws_size,
                              hipStream_t stream) {
    const float* x   = (const float*)d_in[0];
    const float* s   = (const float*)d_in[1];
    const float* fw1 = (const float*)d_in[2];
    const float* fb1 = (const float*)d_in[3];
    const float* fw2 = (const float*)d_in[4];
    const float* fb2 = (const float*)d_in[5];
    const float* fw3 = (const float*)d_in[6];
    const float* fb3 = (const float*)d_in[7];
    const float* ew1 = (const float*)d_in[8];
    const float* eb1 = (const float*)d_in[9];
    const float* ew3 = (const float*)d_in[10];
    const float* eb3 = (const float*)d_in[11];
    float* out = (float*)d_out;

    const size_t ws_need = (size_t)65 * 4096 * sizeof(unsigned short);  // 532,480 B
    const int use_ws = (ws_size >= ws_need) && (((uintptr_t)d_ws & 15) == 0);
    unsigned short* w3img = (unsigned short*)d_ws;

    if (use_ws) prepass<<<dim3(65), dim3(256), 0, stream>>>(ew3, eb3, w3img);
    moe_fused<<<dim3(NBLK), dim3(256), 0, stream>>>(x, s, fw1, fb1, fw2, fb2, fw3, fb3,
                                                    ew1, eb1, ew3, eb3,
                                                    w3img, use_ws, out);
}

// Round 3
// 134.547 us; speedup vs baseline: 2.7250x; 1.3727x over previous
//
#include <hip/hip_runtime.h>
#include <hip/hip_bf16.h>
#include <math.h>

// B=32,T=512 -> NTOK=16384 tokens; F=64; H=64; E=32
#define NTOK 16384

typedef __attribute__((ext_vector_type(8))) short short8;   // 8 bf16 (MFMA A/B)
typedef __attribute__((ext_vector_type(4))) float f32x4;    // MFMA acc

__device__ __forceinline__ unsigned short bf16_rne(float x) {
    unsigned int u = __float_as_uint(x);
    u += 0x7fffu + ((u >> 16) & 1u);
    return (unsigned short)(u >> 16);
}
__device__ __forceinline__ unsigned pack_bf16(float a, float b) {
    union { __hip_bfloat162 h; unsigned u; } cv;
    cv.h = __float22bfloat162_rn(make_float2(a, b));
    return cv.u;
}
__device__ __forceinline__ float eluf(float z) {
    return z > 0.0f ? z : (__expf(z) - 1.0f);
}

// ---------------- prepass: fragment-major bf16 B images ----------------
// slot f (0..63): B = ew3[f] (rows k=h, cols n) ; slot 64: B = eb3 (rows e, cols n)
// image[f][idx] uint4, idx = c*256 + u*64 + lane:
//   element j of lane's short8 = B[c*32 + (lane>>4)*8 + j][u*16 + (lane&15)]
__global__ __launch_bounds__(256)
void prepass(const float* __restrict__ ew3, const float* __restrict__ eb3,
             unsigned short* __restrict__ ws) {
    __shared__ float tile[64 * 65];
    const int bid = blockIdx.x, tid = threadIdx.x;
    const float* src = (bid < 64) ? (ew3 + (size_t)bid * 4096) : eb3;

    const int r = tid >> 2, c0 = (tid & 3) * 16;
    #pragma unroll
    for (int j = 0; j < 4; ++j) {
        float4 v = *(const float4*)(src + r * 64 + c0 + j * 4);
        tile[r * 65 + c0 + j * 4 + 0] = v.x;
        tile[r * 65 + c0 + j * 4 + 1] = v.y;
        tile[r * 65 + c0 + j * 4 + 2] = v.z;
        tile[r * 65 + c0 + j * 4 + 3] = v.w;
    }
    __syncthreads();

    uint4* dst = (uint4*)(ws + (size_t)bid * 4096);
    #pragma unroll
    for (int it = 0; it < 2; ++it) {
        const int idx = tid + it * 256;
        const int c = idx >> 8, u = (idx >> 6) & 3, l = idx & 63;
        const int m = l & 15, q = (l >> 4) & 3;
        const int rb = c * 32 + q * 8, col = u * 16 + m;
        unsigned pw[4];
        #pragma unroll
        for (int p = 0; p < 4; ++p) {
            unsigned lo = bf16_rne(tile[(rb + 2 * p    ) * 65 + col]);
            unsigned hi = bf16_rne(tile[(rb + 2 * p + 1) * 65 + col]);
            pw[p] = lo | (hi << 16);
        }
        uint4 pk; pk.x = pw[0]; pk.y = pw[1]; pk.z = pw[2]; pk.w = pw[3];
        dst[idx] = pk;
    }
}

// ---------------- main fused kernel ----------------
// grid = 1024 blocks x 256 thr; block = 16 tokens; wave w owns f in [w*16, w*16+16)
// (K-split over features) -> 4 waves/SIMD, zero barriers inside the f-loop.
__global__ __launch_bounds__(256, 4)
void moe_fused(const float* __restrict__ x,   const float* __restrict__ s,
               const float* __restrict__ fw1, const float* __restrict__ fb1,
               const float* __restrict__ fw2, const float* __restrict__ fb2,
               const float* __restrict__ fw3, const float* __restrict__ fb3,
               const float* __restrict__ ew1, const float* __restrict__ eb1,
               const float* __restrict__ ew3, const float* __restrict__ eb3,
               const unsigned short* __restrict__ w3img, int use_ws,
               float* __restrict__ out)
{
    __shared__ float wts[16 * 65];                 // gate weights fp32 [t][f]
    __shared__ __align__(16) float ped[4][16 * 68]; // per-wave partial C [t][k]

    const int tid = threadIdx.x;
    const int wv = tid >> 6, lane = tid & 63;
    const int tokbase = blockIdx.x * 16;

    // ---- gating: wave computes softmax gate for its 4 tokens ----
    {
        const int t0w = wv * 4;
        const float* xw = x + (size_t)(tokbase + t0w) * 64;
        const float* sw = s + (size_t)(tokbase + t0w) * 32;
        float g[4];
        const float b0 = fb1[lane] + fb2[lane];
        #pragma unroll
        for (int t = 0; t < 4; ++t) g[t] = b0;
        for (int f = 0; f < 64; ++f) {
            const float w = fw1[f * 64 + lane];
            #pragma unroll
            for (int t = 0; t < 4; ++t) g[t] = fmaf(xw[t * 64 + f], w, g[t]);
        }
        for (int e = 0; e < 32; ++e) {
            const float w = fw2[e * 64 + lane];
            #pragma unroll
            for (int t = 0; t < 4; ++t) g[t] = fmaf(sw[t * 32 + e], w, g[t]);
        }
        #pragma unroll
        for (int t = 0; t < 4; ++t) g[t] = eluf(g[t]);

        float lg[4];
        const float b3 = fb3[lane];
        #pragma unroll
        for (int t = 0; t < 4; ++t) lg[t] = b3;
        for (int h = 0; h < 64; ++h) {
            const float w = fw3[h * 64 + lane];
            #pragma unroll
            for (int t = 0; t < 4; ++t) {
                const float ev = __int_as_float(
                    __builtin_amdgcn_readlane(__float_as_int(g[t]), h));
                lg[t] = fmaf(ev, w, lg[t]);
            }
        }
        #pragma unroll
        for (int t = 0; t < 4; ++t) {
            float mx = lg[t];
            #pragma unroll
            for (int off = 32; off > 0; off >>= 1) mx = fmaxf(mx, __shfl_xor(mx, off));
            const float p = __expf(lg[t] - mx);
            float sm = p;
            #pragma unroll
            for (int off = 32; off > 0; off >>= 1) sm += __shfl_xor(sm, off);
            wts[(t0w + t) * 65 + lane] = p / sm;
        }
    }
    __syncthreads();

    // ---- K-split MFMA main loop: wave tile = 16 tok x 64 out, f in [f0, f0+16) ----
    const int m = tid & 15, quad = (tid >> 4) & 3;
    const int f0 = wv * 16;
    f32x4 acc[4];
    #pragma unroll
    for (int u = 0; u < 4; ++u) acc[u] = (f32x4){0.f, 0.f, 0.f, 0.f};

    const float* xcol = x + (size_t)(tokbase + m) * 64;   // this lane's token row

    for (int ff = 0; ff < 16; ++ff) {
        const int f = f0 + ff;

        // B fragments: one 16B load per (kchunk, ntile) from the frag-major image
        short8 b[2][4];
        if (use_ws) {
            const uint4* bp = (const uint4*)(w3img + (size_t)f * 4096);
            #pragma unroll
            for (int c = 0; c < 2; ++c)
                #pragma unroll
                for (int u = 0; u < 4; ++u) {
                    uint4 v = bp[c * 256 + u * 64 + lane];
                    b[c][u] = *(short8*)&v;
                }
        } else {
            #pragma unroll
            for (int c = 0; c < 2; ++c)
                #pragma unroll
                for (int u = 0; u < 4; ++u) {
                    const float* wp = ew3 + (size_t)f * 4096
                                    + (size_t)(c * 32 + quad * 8) * 64 + u * 16 + m;
                    unsigned pw[4];
                    #pragma unroll
                    for (int p = 0; p < 4; ++p)
                        pw[p] = pack_bf16(wp[(2 * p) * 64], wp[(2 * p + 1) * 64]);
                    uint4 v; v.x = pw[0]; v.y = pw[1]; v.z = pw[2]; v.w = pw[3];
                    b[c][u] = *(short8*)&v;
                }
        }

        // A fragments in-register: a[c] element j = bf16(wt * elu(x*w1 + b1))
        const float xv = xcol[f];
        const float wt = wts[m * 65 + f];
        short8 a[2];
        #pragma unroll
        for (int c = 0; c < 2; ++c) {
            const float* w1p = ew1 + f * 64 + c * 32 + quad * 8;
            const float* b1p = eb1 + f * 64 + c * 32 + quad * 8;
            const float4 w1a = *(const float4*)(w1p);
            const float4 w1b = *(const float4*)(w1p + 4);
            const float4 b1a = *(const float4*)(b1p);
            const float4 b1b = *(const float4*)(b1p + 4);
            float v0 = wt * eluf(fmaf(xv, w1a.x, b1a.x));
            float v1 = wt * eluf(fmaf(xv, w1a.y, b1a.y));
            float v2 = wt * eluf(fmaf(xv, w1a.z, b1a.z));
            float v3 = wt * eluf(fmaf(xv, w1a.w, b1a.w));
            float v4 = wt * eluf(fmaf(xv, w1b.x, b1b.x));
            float v5 = wt * eluf(fmaf(xv, w1b.y, b1b.y));
            float v6 = wt * eluf(fmaf(xv, w1b.z, b1b.z));
            float v7 = wt * eluf(fmaf(xv, w1b.w, b1b.w));
            uint4 av;
            av.x = pack_bf16(v0, v1); av.y = pack_bf16(v2, v3);
            av.z = pack_bf16(v4, v5); av.w = pack_bf16(v6, v7);
            a[c] = *(short8*)&av;
        }

        #pragma unroll
        for (int u = 0; u < 4; ++u) {
            acc[u] = __builtin_amdgcn_mfma_f32_16x16x32_bf16(a[0], b[0][u], acc[u], 0, 0, 0);
            acc[u] = __builtin_amdgcn_mfma_f32_16x16x32_bf16(a[1], b[1][u], acc[u], 0, 0, 0);
        }
    }

    // ---- bias K-chunk: out += w_t @ eb3 ; wave 0 -> e 0..31, wave 1 -> e 32..63 ----
    if (wv < 2) {
        const int e0 = wv * 32 + quad * 8;
        float v[8];
        #pragma unroll
        for (int j = 0; j < 8; ++j) v[j] = wts[m * 65 + e0 + j];
        uint4 av;
        av.x = pack_bf16(v[0], v[1]); av.y = pack_bf16(v[2], v[3]);
        av.z = pack_bf16(v[4], v[5]); av.w = pack_bf16(v[6], v[7]);
        short8 a = *(short8*)&av;

        short8 b[4];
        if (use_ws) {
            const uint4* bp = (const uint4*)(w3img + (size_t)64 * 4096);
            #pragma unroll
            for (int u = 0; u < 4; ++u) {
                uint4 bv = bp[wv * 256 + u * 64 + lane];
                b[u] = *(short8*)&bv;
            }
        } else {
            #pragma unroll
            for (int u = 0; u < 4; ++u) {
                const float* wp = eb3 + (size_t)e0 * 64 + u * 16 + m;
                unsigned pw[4];
                #pragma unroll
                for (int p = 0; p < 4; ++p)
                    pw[p] = pack_bf16(wp[(2 * p) * 64], wp[(2 * p + 1) * 64]);
                uint4 bv; bv.x = pw[0]; bv.y = pw[1]; bv.z = pw[2]; bv.w = pw[3];
                b[u] = *(short8*)&bv;
            }
        }
        #pragma unroll
        for (int u = 0; u < 4; ++u)
            acc[u] = __builtin_amdgcn_mfma_f32_16x16x32_bf16(a, b[u], acc[u], 0, 0, 0);
    }

    // ---- K-split reduction through LDS (C layout: col=lane&15, row=quad*4+r) ----
    #pragma unroll
    for (int u = 0; u < 4; ++u)
        #pragma unroll
        for (int r = 0; r < 4; ++r)
            ped[wv][(quad * 4 + r) * 68 + u * 16 + m] = acc[u][r];
    __syncthreads();

    const int t = tid >> 4, kq = tid & 15;
    const float4 p0 = *(const float4*)&ped[0][t * 68 + kq * 4];
    const float4 p1 = *(const float4*)&ped[1][t * 68 + kq * 4];
    const float4 p2 = *(const float4*)&ped[2][t * 68 + kq * 4];
    const float4 p3 = *(const float4*)&ped[3][t * 68 + kq * 4];
    float4 o;
    o.x = (p0.x + p1.x) + (p2.x + p3.x);
    o.y = (p0.y + p1.y) + (p2.y + p3.y);
    o.z = (p0.z + p1.z) + (p2.z + p3.z);
    o.w = (p0.w + p1.w) + (p2.w + p3.w);
    *(float4*)(out + (size_t)(tokbase + t) * 64 + kq * 4) = o;
}

extern "C" void kernel_launch(void* const* d_in, const int* in_sizes, int n_in,
                              void* d_out, int out_size, void* d_ws, size_t ws_size,
                              hipStream_t stream) {
    const float* x   = (const float*)d_in[0];
    const float* s   = (const float*)d_in[1];
    const float* fw1 = (const float*)d_in[2];
    const float* fb1 = (const float*)d_in[3];
    const float* fw2 = (const float*)d_in[4];
    const float* fb2 = (const float*)d_in[5];
    const float* fw3 = (const float*)d_in[6];
    const float* fb3 = (const float*)d_in[7];
    const float* ew1 = (const float*)d_in[8];
    const float* eb1 = (const float*)d_in[9];
    const float* ew3 = (const float*)d_in[10];
    const float* eb3 = (const float*)d_in[11];
    float* out = (float*)d_out;

    const size_t ws_need = (size_t)65 * 4096 * sizeof(unsigned short);  // 532,480 B
    const int use_ws = (ws_size >= ws_need) && (((uintptr_t)d_ws & 15) == 0);
    unsigned short* w3img = (unsigned short*)d_ws;

    if (use_ws) prepass<<<dim3(65), dim3(256), 0, stream>>>(ew3, eb3, w3img);
    moe_fused<<<dim3(NTOK / 16), dim3(256), 0, stream>>>(x, s, fw1, fb1, fw2, fb2,
                                                         fw3, fb3, ew1, eb1, ew3, eb3,
                                                         w3img, use_ws, out);
}